// Round 11
// baseline (326.377 us; speedup 1.0000x reference)
//
#include <hip/hip_runtime.h>
#include <hip/hip_bf16.h>
#include <math.h>

#define N_NODES 50000
#define N_EDGES 400000
#define DIM 16
#define BOND 4
#define NCHUNK 25000  // N_EDGES / 16
#define EDGE_GRID 1024         // 4 blocks/CU resident at VGPR<=128
#define E_BLOCKS 1563          // ceil(N_EDGES/256)
#define PRE_BASE (E_BLOCKS - 68)
#define SCAN_TILE 1024
#define SCAN_BLOCKS 49         // ceil(N_NODES/1024)
#define NGROUPS 3125           // N_NODES / 16
#define GATHER_GRID 1024       // grid-stride: each block stages weights once
                               // for ~3 node-groups (round-9 lesson inverted)

typedef __attribute__((ext_vector_type(8))) short short8;
typedef __attribute__((ext_vector_type(4))) float f32x4;

__device__ __forceinline__ float bf16_to_f32(unsigned short v) {
  return __uint_as_float(((unsigned int)v) << 16);
}

// ---------------------------------------------------------------------------
// K0 (setup): lin0 (ids < N), deg_count+rank (ids < E), and M_B = U_B@V_B /
// M_A = U_A@V_A on the last 68 blocks.
// ---------------------------------------------------------------------------
__global__ __launch_bounds__(256) void setup_kernel(
    const float* __restrict__ x, const float* __restrict__ W_lin0,
    const float* __restrict__ b_lin0, const int* __restrict__ ei,
    const float* __restrict__ U_B, const float* __restrict__ V_B,
    const float* __restrict__ U_A, const float* __restrict__ V_A,
    float* __restrict__ out, int* __restrict__ degI, int* __restrict__ rank,
    float* __restrict__ M_B, float* __restrict__ M_A) {
  __shared__ float sW0[256];
  __shared__ float sb0[16];
  int t = threadIdx.x;
  sW0[t] = W_lin0[t];
  if (t < 16) sb0[t] = b_lin0[t];
  __syncthreads();

  int gid = blockIdx.x * 256 + t;

  if (gid < N_NODES) {  // lin0
    float xr[16];
#pragma unroll
    for (int d = 0; d < 16; ++d) xr[d] = x[gid * 16 + d];
#pragma unroll
    for (int k = 0; k < 16; ++k) {
      float acc = sb0[k];
#pragma unroll
      for (int d = 0; d < 16; ++d) acc += xr[d] * sW0[d * 16 + k];
      out[gid * 16 + k] = fmaxf(acc, 0.f);
    }
  }

  if (gid < N_EDGES) {  // deg_count + rank
    rank[gid] = atomicAdd(&degI[ei[N_EDGES + gid]], 1);
  }

  if (blockIdx.x >= PRE_BASE) {  // M_B / M_A precompute
    int w = (blockIdx.x - PRE_BASE) * 4 + (t >> 6);
    int lane = t & 63;
    float partial = 0.f;
    if (w < 256) {
      int i = w >> 4, j = w & 15;
#pragma unroll
      for (int r8 = 0; r8 < 8; ++r8) {
        int r = lane + 64 * r8;
        partial += U_B[i * 512 + r] * V_B[r * 16 + j];
      }
    } else if (w < 272) {
      int a = (w - 256) >> 2, b = (w - 256) & 3;
#pragma unroll
      for (int r8 = 0; r8 < 8; ++r8) {
        int r = lane + 64 * r8;
        partial += U_A[a * 512 + r] * V_A[r * 4 + b];
      }
    }
#pragma unroll
    for (int off = 32; off > 0; off >>= 1)
      partial += __shfl_down(partial, off);
    if (lane == 0) {
      if (w < 256) M_B[w] = partial;
      else if (w < 272) M_A[w - 256] = partial;
    }
  }
}

// ---------------------------------------------------------------------------
// K1: single-dispatch exclusive scan of degI -> row_off, decoupled lookback.
// ---------------------------------------------------------------------------
__global__ __launch_bounds__(256) void scan_kernel(
    const int* __restrict__ degI, int* ticket, int* st,
    int* __restrict__ row_off) {
  __shared__ int sdata[256];
  __shared__ int s_tile;
  __shared__ int s_base;
  int t = threadIdx.x;
  if (t == 0) s_tile = atomicAdd(ticket, 1);
  __syncthreads();
  int tile = s_tile;
  int n0 = tile * SCAN_TILE + t * 4;

  int d0 = (n0 + 0 < N_NODES) ? degI[n0 + 0] : 0;
  int d1 = (n0 + 1 < N_NODES) ? degI[n0 + 1] : 0;
  int d2 = (n0 + 2 < N_NODES) ? degI[n0 + 2] : 0;
  int d3 = (n0 + 3 < N_NODES) ? degI[n0 + 3] : 0;
  int tsum = d0 + d1 + d2 + d3;
  sdata[t] = tsum;
  __syncthreads();
  for (int off = 1; off < 256; off <<= 1) {
    int v = (t >= off) ? sdata[t - off] : 0;
    __syncthreads();
    sdata[t] += v;
    __syncthreads();
  }
  int excl = sdata[t] - tsum;
  int agg = sdata[255];

  if (t == 0) {
    if (tile == 0) {
      atomicExch(&st[0], (agg << 2) | 2);
      s_base = 0;
    } else {
      atomicExch(&st[tile], (agg << 2) | 1);
      int run = 0, idx = tile - 1;
      while (true) {
        int w = atomicAdd(&st[idx], 0);
        int stt = w & 3;
        if (stt == 2) { run += (w >> 2); break; }
        if (stt == 1) { run += (w >> 2); --idx; }
      }
      atomicExch(&st[tile], ((run + agg) << 2) | 2);
      s_base = run;
    }
  }
  __syncthreads();

  int pre = s_base + excl;
  if (n0 + 0 < N_NODES) row_off[n0 + 0] = pre;
  pre += d0;
  if (n0 + 1 < N_NODES) row_off[n0 + 1] = pre;
  pre += d1;
  if (n0 + 2 < N_NODES) row_off[n0 + 2] = pre;
  pre += d2;
  if (n0 + 3 < N_NODES) row_off[n0 + 3] = pre;
  if (tile == SCAN_BLOCKS - 1 && t == 0) row_off[N_NODES] = N_EDGES;
}

// ---------------------------------------------------------------------------
// K2: slot[e] = row_off[dst[e]] + rank[e]. Pure gather, once per run.
// ---------------------------------------------------------------------------
__global__ __launch_bounds__(256) void slot_kernel(
    const int* __restrict__ ei, const int* __restrict__ row_off,
    const int* __restrict__ rank, int* __restrict__ slot) {
  int e = blockIdx.x * 256 + threadIdx.x;
  if (e < N_EDGES) slot[e] = row_off[ei[N_EDGES + e]] + rank[e];
}

// ---------------------------------------------------------------------------
// K3 (MFMA, 3-deep software pipeline): CONVERGED at ~43.5us across rounds
// 5-10 (occupancy 3->4 blocks/CU, pipeline 2->3 deep, VALU packing all
// moved <=2us). Do not touch without disasm evidence.
// NOTE: no min-occupancy launch_bounds (round 7: hipcc squeezed VGPR to 64,
// 450 MB/dispatch scratch spill).
// ---------------------------------------------------------------------------
__global__ __launch_bounds__(256) void edge_msg_mfma_kernel(
    const int* __restrict__ ei, const float* __restrict__ ea,
    const float* __restrict__ We1, const float* __restrict__ be1,
    const float* __restrict__ We2, const float* __restrict__ be2,
    const float* __restrict__ out, const int* __restrict__ slot,
    unsigned short* __restrict__ m_bufh) {
  __shared__ float sW1T[128];  // [(p*16+s)*4 + j] = We1[j*32 + 2s+p]
  __shared__ float sbe1[32];   // [p*16+s] = be1[2s+p]
  int t = threadIdx.x;
  if (t < 128) sW1T[t] = We1[(t & 3) * 32 + 2 * ((t >> 2) & 15) + (t >> 6)];
  if (t < 32) sbe1[t] = be1[2 * (t & 15) + (t >> 4)];

  const int lane = t & 63;
  const int q = lane >> 4, n = lane & 15;
  const int p = q >> 1, dbase = (q & 1) * 8;

  short8 bfrag[17];
#pragma unroll
  for (int s = 0; s < 16; ++s) {
    int h = 2 * s + p;
    union { short8 v; __hip_bfloat162 b2[4]; } bf;
#pragma unroll
    for (int jj = 0; jj < 4; ++jj) {
      float2 w;
      w.x = We2[h * 256 + (dbase + 2 * jj) * 16 + n];
      w.y = We2[h * 256 + (dbase + 2 * jj + 1) * 16 + n];
      bf.b2[jj] = __float22bfloat162_rn(w);
    }
    bfrag[s] = bf.v;
  }
  {
    union { short8 v; __hip_bfloat162 b2[4]; } bf;
#pragma unroll
    for (int jj = 0; jj < 4; ++jj) {
      float2 w;
      if (q < 2) {
        w.x = be2[(dbase + 2 * jj) * 16 + n];
        w.y = be2[(dbase + 2 * jj + 1) * 16 + n];
      } else {
        w.x = 0.f; w.y = 0.f;
      }
      bf.b2[jj] = __float22bfloat162_rn(w);
    }
    bfrag[16] = bf.v;
  }
  __syncthreads();

  const int wave = blockIdx.x * 4 + (t >> 6);
  const int nw = EDGE_GRID * 4;

  // ---- pipeline prologue ----
  int src2 = 0;
  float4 avP = {0.f, 0.f, 0.f, 0.f}, avQ = {0.f, 0.f, 0.f, 0.f};
  float4 oP0 = {0.f, 0.f, 0.f, 0.f}, oP1 = {0.f, 0.f, 0.f, 0.f};
  float4 oQ0 = {0.f, 0.f, 0.f, 0.f}, oQ1 = {0.f, 0.f, 0.f, 0.f};
  {
    int src0 = 0, src1 = 0;
    if (wave < NCHUNK) {
      src0 = ei[wave * 16 + n];
      avP = ((const float4*)ea)[wave * 16 + n];
    }
    if (wave + nw < NCHUNK) {
      src1 = ei[(wave + nw) * 16 + n];
      avQ = ((const float4*)ea)[(wave + nw) * 16 + n];
    }
    if (wave + 2 * nw < NCHUNK) src2 = ei[(wave + 2 * nw) * 16 + n];
    if (wave < NCHUNK) {
      const float4* op = (const float4*)(out + src0 * 16 + dbase);
      oP0 = op[0];
      oP1 = op[1];
    }
    if (wave + nw < NCHUNK) {
      const float4* op = (const float4*)(out + src1 * 16 + dbase);
      oQ0 = op[0];
      oQ1 = op[1];
    }
  }

  for (int c = wave; c < NCHUNK; c += nw) {
    int src3 = 0;
    float4 avN = {0.f, 0.f, 0.f, 0.f};
    if (c + 3 * nw < NCHUNK) src3 = ei[(c + 3 * nw) * 16 + n];
    if (c + 2 * nw < NCHUNK) avN = ((const float4*)ea)[(c + 2 * nw) * 16 + n];
    float4 oR0 = {0.f, 0.f, 0.f, 0.f}, oR1 = {0.f, 0.f, 0.f, 0.f};
    if (c + 2 * nw < NCHUNK) {
      const float4* op = (const float4*)(out + src2 * 16 + dbase);
      oR0 = op[0];
      oR1 = op[1];
    }
    int4 sl = *(const int4*)(slot + c * 16 + q * 4);

    float o[8] = {oP0.x, oP0.y, oP0.z, oP0.w, oP1.x, oP1.y, oP1.z, oP1.w};
    f32x4 acc = {0.f, 0.f, 0.f, 0.f};
#pragma unroll
    for (int s = 0; s < 16; ++s) {
      float4 wj = *(const float4*)&sW1T[(p * 16 + s) * 4];
      float he_s = fmaxf(sbe1[p * 16 + s] + avP.x * wj.x + avP.y * wj.y +
                             avP.z * wj.z + avP.w * wj.w,
                         0.f);
      union { short8 v; __hip_bfloat162 b2[4]; } af;
#pragma unroll
      for (int jj = 0; jj < 4; ++jj) {
        float2 pr;
        pr.x = he_s * o[2 * jj];
        pr.y = he_s * o[2 * jj + 1];
        af.b2[jj] = __float22bfloat162_rn(pr);
      }
      acc = __builtin_amdgcn_mfma_f32_16x16x32_bf16(af.v, bfrag[s], acc, 0, 0, 0);
    }
    {  // bias step
      union { short8 v; __hip_bfloat162 b2[4]; } af;
#pragma unroll
      for (int jj = 0; jj < 4; ++jj) {
        float2 pr;
        if (q < 2) { pr.x = o[2 * jj]; pr.y = o[2 * jj + 1]; }
        else { pr.x = 0.f; pr.y = 0.f; }
        af.b2[jj] = __float22bfloat162_rn(pr);
      }
      acc = __builtin_amdgcn_mfma_f32_16x16x32_bf16(af.v, bfrag[16], acc, 0, 0, 0);
    }

    __hip_bfloat16 b0 = __float2bfloat16(acc[0]);
    __hip_bfloat16 b1 = __float2bfloat16(acc[1]);
    __hip_bfloat16 b2 = __float2bfloat16(acc[2]);
    __hip_bfloat16 b3 = __float2bfloat16(acc[3]);
    m_bufh[(size_t)sl.x * 16 + n] = *(unsigned short*)&b0;
    m_bufh[(size_t)sl.y * 16 + n] = *(unsigned short*)&b1;
    m_bufh[(size_t)sl.z * 16 + n] = *(unsigned short*)&b2;
    m_bufh[(size_t)sl.w * 16 + n] = *(unsigned short*)&b3;

    oP0 = oQ0; oP1 = oQ1; oQ0 = oR0; oQ1 = oR1;
    avP = avQ; avQ = avN;
    src2 = src3;
  }
}

// ---------------------------------------------------------------------------
// K4 (fused gather + GRU [+ final tail on last iter]): 16 lanes per node,
// GRID-STRIDE over node groups (1024 blocks x ~3 groups): weight staging
// (1904 words + barrier, previously paid by 3125 blocks) now paid once per
// ~3 groups -- inverse of round-9's regression mechanism. Hot loop unchanged
// from round-8 measured-best: hk hoisted, segment sum unrolled x8.
// ---------------------------------------------------------------------------
__global__ __launch_bounds__(256) void gather_gru_kernel(
    const int* __restrict__ row_off, const unsigned short* __restrict__ m_bufh,
    const float* __restrict__ Wroot, const float* __restrict__ bconv,
    const float* __restrict__ Wih, const float* __restrict__ bih,
    const float* __restrict__ Whh, const float* __restrict__ bhh,
    float* __restrict__ out, int do_final, const int* __restrict__ node_type,
    const float* __restrict__ Wlin1, const float* __restrict__ blin1,
    const float* __restrict__ Wup, const float* __restrict__ bup,
    const float* __restrict__ Wdown, const float* __restrict__ bdown,
    const float* __restrict__ M_B, const float* __restrict__ M_A,
    const float* __restrict__ wedge, const float* __restrict__ Wline,
    const float* __restrict__ bline, float* __restrict__ res) {
  __shared__ float sWr[256];
  __shared__ float sWihT[768];  // [g*256 + d*16 + k] = Wih[(g*16+k)*16+d]
  __shared__ float sWhhT[768];
  __shared__ float sb[112];     // bconv[16] | bih[48] | bhh[48]
  int t = threadIdx.x;
  {
    int kk = t >> 4, dd = t & 15;
    sWr[t] = Wroot[t];
#pragma unroll
    for (int g = 0; g < 3; ++g) {
      sWihT[g * 256 + dd * 16 + kk] = Wih[g * 256 + t];
      sWhhT[g * 256 + dd * 16 + kk] = Whh[g * 256 + t];
    }
    if (t < 16) sb[t] = bconv[t];
    else if (t < 64) sb[t] = bih[t - 16];
    else if (t < 112) sb[t] = bhh[t - 64];
  }
  __syncthreads();

  int k = t & 15;
  for (int g = blockIdx.x; g < NGROUPS; g += GATHER_GRID) {
    int n = g * 16 + (t >> 4);
    int s0 = row_off[n], s1 = row_off[n + 1];

    float hk = out[n * 16 + k];  // independent load, in flight during the sum

    float aggk = 0.f;
    int j = s0;
    for (; j + 7 < s1; j += 8) {
      float a0 = bf16_to_f32(m_bufh[(size_t)(j + 0) * 16 + k]);
      float a1 = bf16_to_f32(m_bufh[(size_t)(j + 1) * 16 + k]);
      float a2 = bf16_to_f32(m_bufh[(size_t)(j + 2) * 16 + k]);
      float a3 = bf16_to_f32(m_bufh[(size_t)(j + 3) * 16 + k]);
      float a4 = bf16_to_f32(m_bufh[(size_t)(j + 4) * 16 + k]);
      float a5 = bf16_to_f32(m_bufh[(size_t)(j + 5) * 16 + k]);
      float a6 = bf16_to_f32(m_bufh[(size_t)(j + 6) * 16 + k]);
      float a7 = bf16_to_f32(m_bufh[(size_t)(j + 7) * 16 + k]);
      aggk += ((a0 + a1) + (a2 + a3)) + ((a4 + a5) + (a6 + a7));
    }
    for (; j + 3 < s1; j += 4) {
      float a0 = bf16_to_f32(m_bufh[(size_t)(j + 0) * 16 + k]);
      float a1 = bf16_to_f32(m_bufh[(size_t)(j + 1) * 16 + k]);
      float a2 = bf16_to_f32(m_bufh[(size_t)(j + 2) * 16 + k]);
      float a3 = bf16_to_f32(m_bufh[(size_t)(j + 3) * 16 + k]);
      aggk += (a0 + a1) + (a2 + a3);
    }
    for (; j < s1; ++j) aggk += bf16_to_f32(m_bufh[(size_t)j * 16 + k]);
    float sc = 1.f / fmaxf((float)(s1 - s0), 1.f);

    float mk = sb[k] + aggk * sc;
#pragma unroll
    for (int d = 0; d < 16; ++d) mk += __shfl(hk, d, 16) * sWr[d * 16 + k];
    mk = fmaxf(mk, 0.f);

    float gir = sb[16 + k], giz = sb[32 + k], gin = sb[48 + k];
    float ghr = sb[64 + k], ghz = sb[80 + k], ghn = sb[96 + k];
#pragma unroll
    for (int d = 0; d < 16; ++d) {
      float md = __shfl(mk, d, 16);
      float hd = __shfl(hk, d, 16);
      gir += md * sWihT[d * 16 + k];
      giz += md * sWihT[256 + d * 16 + k];
      gin += md * sWihT[512 + d * 16 + k];
      ghr += hd * sWhhT[d * 16 + k];
      ghz += hd * sWhhT[256 + d * 16 + k];
      ghn += hd * sWhhT[512 + d * 16 + k];
    }
    float r = 1.f / (1.f + __expf(-(gir + ghr)));
    float z = 1.f / (1.f + __expf(-(giz + ghz)));
    float xn = gin + r * ghn;
    float ng = 1.f - 2.f / (__expf(2.f * xn) + 1.f);  // tanh, saturates safely
    float hnew = (1.f - z) * ng + z * hk;

    if (!do_final) {
      out[n * 16 + k] = hnew;
    } else {
      // ---- fused tail (only out_edges branch is live) ----
      float p0 = hnew * Wlin1[k * 4 + 0];
      float p1 = hnew * Wlin1[k * 4 + 1];
      float p2 = hnew * Wlin1[k * 4 + 2];
      float p3 = hnew * Wlin1[k * 4 + 3];
#pragma unroll
      for (int msk = 1; msk < 16; msk <<= 1) {
        p0 += __shfl_xor(p0, msk, 16);
        p1 += __shfl_xor(p1, msk, 16);
        p2 += __shfl_xor(p2, msk, 16);
        p3 += __shfl_xor(p3, msk, 16);
      }
      float oe0 = fmaxf(p0 + blin1[0], 0.f);
      float oe1 = fmaxf(p1 + blin1[1], 0.f);
      float oe2 = fmaxf(p2 + blin1[2], 0.f);
      float oe3 = fmaxf(p3 + blin1[3], 0.f);

      bool ev = (node_type[n] == 2);
      float ock = ev ? (bup[k] + oe0 * Wup[k] + oe1 * Wup[16 + k] +
                        oe2 * Wup[32 + k] + oe3 * Wup[48 + k])
                     : hnew;

      float msgBk = 0.f;
#pragma unroll
      for (int d = 0; d < 16; ++d)
        msgBk += __shfl(ock, d, 16) * M_B[d * 16 + k];
      msgBk = fmaxf(msgBk, 0.f);

      float q0 = msgBk * Wdown[k * 4 + 0];
      float q1 = msgBk * Wdown[k * 4 + 1];
      float q2 = msgBk * Wdown[k * 4 + 2];
      float q3 = msgBk * Wdown[k * 4 + 3];
#pragma unroll
      for (int msk = 1; msk < 16; msk <<= 1) {
        q0 += __shfl_xor(q0, msk, 16);
        q1 += __shfl_xor(q1, msk, 16);
        q2 += __shfl_xor(q2, msk, 16);
        q3 += __shfl_xor(q3, msk, 16);
      }
      float mtb0 = q0 + bdown[0], mtb1 = q1 + bdown[1];
      float mtb2 = q2 + bdown[2], mtb3 = q3 + bdown[3];

      float mta0 = fmaxf(oe0 * M_A[0] + oe1 * M_A[4] + oe2 * M_A[8] + oe3 * M_A[12], 0.f);
      float mta1 = fmaxf(oe0 * M_A[1] + oe1 * M_A[5] + oe2 * M_A[9] + oe3 * M_A[13], 0.f);
      float mta2 = fmaxf(oe0 * M_A[2] + oe1 * M_A[6] + oe2 * M_A[10] + oe3 * M_A[14], 0.f);
      float mta3 = fmaxf(oe0 * M_A[3] + oe1 * M_A[7] + oe2 * M_A[11] + oe3 * M_A[15], 0.f);

      float c0 = wedge[0] * (mta0 * mtb0);
      float c1 = wedge[1] * (mta1 * mtb1);
      float c2 = wedge[2] * (mta2 * mtb2);
      float c3 = wedge[3] * (mta3 * mtb3);

      float f0 = oe0 + fmaxf(bline[0] + c0 * Wline[0] + c1 * Wline[4] +
                             c2 * Wline[8] + c3 * Wline[12], 0.f);
      float f1 = oe1 + fmaxf(bline[1] + c0 * Wline[1] + c1 * Wline[5] +
                             c2 * Wline[9] + c3 * Wline[13], 0.f);
      float f2 = oe2 + fmaxf(bline[2] + c0 * Wline[2] + c1 * Wline[6] +
                             c2 * Wline[10] + c3 * Wline[14], 0.f);
      float f3 = oe3 + fmaxf(bline[3] + c0 * Wline[3] + c1 * Wline[7] +
                             c2 * Wline[11] + c3 * Wline[15], 0.f);

      float mx = fmaxf(fmaxf(f0, f1), fmaxf(f2, f3));
      float se = __expf(f0 - mx) + __expf(f1 - mx) + __expf(f2 - mx) +
                 __expf(f3 - mx);
      float lse = mx + __logf(se);
      if (k < 4) {
        float v = (k == 0) ? f0 : (k == 1) ? f1 : (k == 2) ? f2 : f3;
        res[n * 4 + k] = v - lse;
      }
    }
  }
}

// ---------------------------------------------------------------------------
extern "C" void kernel_launch(void* const* d_in, const int* in_sizes, int n_in,
                              void* d_out, int out_size, void* d_ws,
                              size_t ws_size, hipStream_t stream) {
  const float* x       = (const float*)d_in[0];
  const int* node_type = (const int*)d_in[1];
  const int* ei        = (const int*)d_in[2];
  const float* ea      = (const float*)d_in[3];
  const float* W_lin0  = (const float*)d_in[4];
  const float* b_lin0  = (const float*)d_in[5];
  const float* W_root  = (const float*)d_in[6];
  const float* b_conv  = (const float*)d_in[7];
  const float* W_e1    = (const float*)d_in[8];
  const float* b_e1    = (const float*)d_in[9];
  const float* W_e2    = (const float*)d_in[10];
  const float* b_e2    = (const float*)d_in[11];
  const float* W_ih    = (const float*)d_in[12];
  const float* b_ih    = (const float*)d_in[13];
  const float* W_hh    = (const float*)d_in[14];
  const float* b_hh    = (const float*)d_in[15];
  const float* W_lin1  = (const float*)d_in[16];
  const float* b_lin1  = (const float*)d_in[17];
  const float* W_up    = (const float*)d_in[18];
  const float* b_up    = (const float*)d_in[19];
  const float* W_down  = (const float*)d_in[20];
  const float* b_down  = (const float*)d_in[21];
  const float* U_B     = (const float*)d_in[22];
  const float* V_B     = (const float*)d_in[23];
  // d_in[24..25] U_C,V_C and d_in[28..30] w_node,W_lin,b_lin : dead code
  const float* U_A     = (const float*)d_in[26];
  const float* V_A     = (const float*)d_in[27];
  const float* w_edge  = (const float*)d_in[31];
  const float* W_line  = (const float*)d_in[32];
  const float* b_line  = (const float*)d_in[33];

  float* ws    = (float*)d_ws;
  float* out   = ws;                                        // N*16 f32
  unsigned short* m_bufh = (unsigned short*)(out + N_NODES * 16);  // E*16 u16
  float* M_B   = (float*)(m_bufh + (size_t)N_EDGES * 16);   // 256
  float* M_A   = M_B + 256;                                 // 16
  int* degI    = (int*)(M_A + 16);                          // N
  int* ticket  = degI + N_NODES;                            // 1
  int* st      = ticket + 1;                                // 63 (pad)
  int* row_off = st + 63;                                   // N+1
  int* rank    = row_off + N_NODES + 1;                     // E
  int* slot    = rank + N_EDGES;                            // E

  // zero degI + ticket + st in one memset
  hipMemsetAsync(degI, 0, (N_NODES + 64) * sizeof(int), stream);

  setup_kernel<<<E_BLOCKS, 256, 0, stream>>>(x, W_lin0, b_lin0, ei, U_B, V_B,
                                             U_A, V_A, out, degI, rank, M_B,
                                             M_A);
  scan_kernel<<<SCAN_BLOCKS, 256, 0, stream>>>(degI, ticket, st, row_off);
  slot_kernel<<<E_BLOCKS, 256, 0, stream>>>(ei, row_off, rank, slot);

  for (int it = 0; it < 3; ++it) {
    edge_msg_mfma_kernel<<<EDGE_GRID, 256, 0, stream>>>(
        ei, ea, W_e1, b_e1, W_e2, b_e2, out, slot, m_bufh);
    gather_gru_kernel<<<GATHER_GRID, 256, 0, stream>>>(
        row_off, m_bufh, W_root, b_conv, W_ih, b_ih, W_hh, b_hh, out,
        (it == 2) ? 1 : 0, node_type, W_lin1, b_lin1, W_up, b_up, W_down,
        b_down, M_B, M_A, w_edge, W_line, b_line, (float*)d_out);
  }
}

// Round 12
// 290.955 us; speedup vs baseline: 1.1217x; 1.1217x over previous
//
#include <hip/hip_runtime.h>
#include <hip/hip_bf16.h>
#include <math.h>

#define N_NODES 50000
#define N_EDGES 400000
#define DIM 16
#define BOND 4
#define NCHUNK 25000  // N_EDGES / 16
#define EDGE_GRID 1024         // 4 blocks/CU resident at VGPR<=128
#define E_BLOCKS 1563          // ceil(N_EDGES/256)
#define PRE_BASE (E_BLOCKS - 68)
#define SCAN_TILE 1024
#define SCAN_BLOCKS 49         // ceil(N_NODES/1024)

typedef __attribute__((ext_vector_type(8))) short short8;
typedef __attribute__((ext_vector_type(8))) _Float16 half8;
typedef __attribute__((ext_vector_type(4))) float f32x4;

__device__ __forceinline__ float bf16_to_f32(unsigned short v) {
  return __uint_as_float(((unsigned int)v) << 16);
}

// ---------------------------------------------------------------------------
// K0 (setup): lin0 (ids < N), deg_count+rank (ids < E), and M_B = U_B@V_B /
// M_A = U_A@V_A on the last 68 blocks.
// ---------------------------------------------------------------------------
__global__ __launch_bounds__(256) void setup_kernel(
    const float* __restrict__ x, const float* __restrict__ W_lin0,
    const float* __restrict__ b_lin0, const int* __restrict__ ei,
    const float* __restrict__ U_B, const float* __restrict__ V_B,
    const float* __restrict__ U_A, const float* __restrict__ V_A,
    float* __restrict__ out, int* __restrict__ degI, int* __restrict__ rank,
    float* __restrict__ M_B, float* __restrict__ M_A) {
  __shared__ float sW0[256];
  __shared__ float sb0[16];
  int t = threadIdx.x;
  sW0[t] = W_lin0[t];
  if (t < 16) sb0[t] = b_lin0[t];
  __syncthreads();

  int gid = blockIdx.x * 256 + t;

  if (gid < N_NODES) {  // lin0
    float xr[16];
#pragma unroll
    for (int d = 0; d < 16; ++d) xr[d] = x[gid * 16 + d];
#pragma unroll
    for (int k = 0; k < 16; ++k) {
      float acc = sb0[k];
#pragma unroll
      for (int d = 0; d < 16; ++d) acc += xr[d] * sW0[d * 16 + k];
      out[gid * 16 + k] = fmaxf(acc, 0.f);
    }
  }

  if (gid < N_EDGES) {  // deg_count + rank
    rank[gid] = atomicAdd(&degI[ei[N_EDGES + gid]], 1);
  }

  if (blockIdx.x >= PRE_BASE) {  // M_B / M_A precompute
    int w = (blockIdx.x - PRE_BASE) * 4 + (t >> 6);
    int lane = t & 63;
    float partial = 0.f;
    if (w < 256) {
      int i = w >> 4, j = w & 15;
#pragma unroll
      for (int r8 = 0; r8 < 8; ++r8) {
        int r = lane + 64 * r8;
        partial += U_B[i * 512 + r] * V_B[r * 16 + j];
      }
    } else if (w < 272) {
      int a = (w - 256) >> 2, b = (w - 256) & 3;
#pragma unroll
      for (int r8 = 0; r8 < 8; ++r8) {
        int r = lane + 64 * r8;
        partial += U_A[a * 512 + r] * V_A[r * 4 + b];
      }
    }
#pragma unroll
    for (int off = 32; off > 0; off >>= 1)
      partial += __shfl_down(partial, off);
    if (lane == 0) {
      if (w < 256) M_B[w] = partial;
      else if (w < 272) M_A[w - 256] = partial;
    }
  }
}

// ---------------------------------------------------------------------------
// K1: single-dispatch exclusive scan of degI -> row_off, decoupled lookback.
// ---------------------------------------------------------------------------
__global__ __launch_bounds__(256) void scan_kernel(
    const int* __restrict__ degI, int* ticket, int* st,
    int* __restrict__ row_off) {
  __shared__ int sdata[256];
  __shared__ int s_tile;
  __shared__ int s_base;
  int t = threadIdx.x;
  if (t == 0) s_tile = atomicAdd(ticket, 1);
  __syncthreads();
  int tile = s_tile;
  int n0 = tile * SCAN_TILE + t * 4;

  int d0 = (n0 + 0 < N_NODES) ? degI[n0 + 0] : 0;
  int d1 = (n0 + 1 < N_NODES) ? degI[n0 + 1] : 0;
  int d2 = (n0 + 2 < N_NODES) ? degI[n0 + 2] : 0;
  int d3 = (n0 + 3 < N_NODES) ? degI[n0 + 3] : 0;
  int tsum = d0 + d1 + d2 + d3;
  sdata[t] = tsum;
  __syncthreads();
  for (int off = 1; off < 256; off <<= 1) {
    int v = (t >= off) ? sdata[t - off] : 0;
    __syncthreads();
    sdata[t] += v;
    __syncthreads();
  }
  int excl = sdata[t] - tsum;
  int agg = sdata[255];

  if (t == 0) {
    if (tile == 0) {
      atomicExch(&st[0], (agg << 2) | 2);
      s_base = 0;
    } else {
      atomicExch(&st[tile], (agg << 2) | 1);
      int run = 0, idx = tile - 1;
      while (true) {
        int w = atomicAdd(&st[idx], 0);
        int stt = w & 3;
        if (stt == 2) { run += (w >> 2); break; }
        if (stt == 1) { run += (w >> 2); --idx; }
      }
      atomicExch(&st[tile], ((run + agg) << 2) | 2);
      s_base = run;
    }
  }
  __syncthreads();

  int pre = s_base + excl;
  if (n0 + 0 < N_NODES) row_off[n0 + 0] = pre;
  pre += d0;
  if (n0 + 1 < N_NODES) row_off[n0 + 1] = pre;
  pre += d1;
  if (n0 + 2 < N_NODES) row_off[n0 + 2] = pre;
  pre += d2;
  if (n0 + 3 < N_NODES) row_off[n0 + 3] = pre;
  if (tile == SCAN_BLOCKS - 1 && t == 0) row_off[N_NODES] = N_EDGES;
}

// ---------------------------------------------------------------------------
// K2: slot[e] = row_off[dst[e]] + rank[e]. Pure gather, once per run.
// ---------------------------------------------------------------------------
__global__ __launch_bounds__(256) void slot_kernel(
    const int* __restrict__ ei, const int* __restrict__ row_off,
    const int* __restrict__ rank, int* __restrict__ slot) {
  int e = blockIdx.x * 256 + threadIdx.x;
  if (e < N_EDGES) slot[e] = row_off[ei[N_EDGES + e]] + rank[e];
}

// ---------------------------------------------------------------------------
// K3 (MFMA f16, 3-deep software pipeline): structure converged (~43.5us);
// this round swaps the A/B fragments to f16 so products are packed
// v_pk_mul_f16 (4/step) instead of 8 v_mul_f32 + 4 v_cvt_pk_bf16_f32
// (12/step) -- pure VALU-count cut, no layout change (C/D layout is
// dtype-independent). f16 10-bit mantissa >= bf16 8-bit; he,o = O(1).
// NOTE: no min-occupancy launch_bounds (round 7: VGPR squeeze -> 450MB spill).
// ---------------------------------------------------------------------------
__global__ __launch_bounds__(256) void edge_msg_mfma_kernel(
    const int* __restrict__ ei, const float* __restrict__ ea,
    const float* __restrict__ We1, const float* __restrict__ be1,
    const float* __restrict__ We2, const float* __restrict__ be2,
    const float* __restrict__ out, const int* __restrict__ slot,
    unsigned short* __restrict__ m_bufh) {
  __shared__ float sW1T[128];  // [(p*16+s)*4 + j] = We1[j*32 + 2s+p]
  __shared__ float sbe1[32];   // [p*16+s] = be1[2s+p]
  int t = threadIdx.x;
  if (t < 128) sW1T[t] = We1[(t & 3) * 32 + 2 * ((t >> 2) & 15) + (t >> 6)];
  if (t < 32) sbe1[t] = be1[2 * (t & 15) + (t >> 4)];

  const int lane = t & 63;
  const int q = lane >> 4, n = lane & 15;
  const int p = q >> 1, dbase = (q & 1) * 8;

  half8 bfrag[17];
#pragma unroll
  for (int s = 0; s < 16; ++s) {
    int h = 2 * s + p;
    half8 bv;
#pragma unroll
    for (int jj = 0; jj < 4; ++jj) {
      bv[2 * jj] = (_Float16)We2[h * 256 + (dbase + 2 * jj) * 16 + n];
      bv[2 * jj + 1] = (_Float16)We2[h * 256 + (dbase + 2 * jj + 1) * 16 + n];
    }
    bfrag[s] = bv;
  }
  {
    half8 bv;
#pragma unroll
    for (int jj = 0; jj < 4; ++jj) {
      if (q < 2) {
        bv[2 * jj] = (_Float16)be2[(dbase + 2 * jj) * 16 + n];
        bv[2 * jj + 1] = (_Float16)be2[(dbase + 2 * jj + 1) * 16 + n];
      } else {
        bv[2 * jj] = (_Float16)0.f;
        bv[2 * jj + 1] = (_Float16)0.f;
      }
    }
    bfrag[16] = bv;
  }
  __syncthreads();

  const int wave = blockIdx.x * 4 + (t >> 6);
  const int nw = EDGE_GRID * 4;

  // ---- pipeline prologue ----
  // invariant at loop top (computing chunk c):
  //   oP: out-gather for c      (issued 2 iters ago, arrived)
  //   oQ: out-gather for c+nw   (issued 1 iter ago, in flight)
  //   src2: ei for c+2nw        (arrived)
  //   avP: ea for c (arrived); avQ: ea for c+nw (in flight)
  int src2 = 0;
  float4 avP = {0.f, 0.f, 0.f, 0.f}, avQ = {0.f, 0.f, 0.f, 0.f};
  float4 oP0 = {0.f, 0.f, 0.f, 0.f}, oP1 = {0.f, 0.f, 0.f, 0.f};
  float4 oQ0 = {0.f, 0.f, 0.f, 0.f}, oQ1 = {0.f, 0.f, 0.f, 0.f};
  {
    int src0 = 0, src1 = 0;
    if (wave < NCHUNK) {
      src0 = ei[wave * 16 + n];
      avP = ((const float4*)ea)[wave * 16 + n];
    }
    if (wave + nw < NCHUNK) {
      src1 = ei[(wave + nw) * 16 + n];
      avQ = ((const float4*)ea)[(wave + nw) * 16 + n];
    }
    if (wave + 2 * nw < NCHUNK) src2 = ei[(wave + 2 * nw) * 16 + n];
    if (wave < NCHUNK) {
      const float4* op = (const float4*)(out + src0 * 16 + dbase);
      oP0 = op[0];
      oP1 = op[1];
    }
    if (wave + nw < NCHUNK) {
      const float4* op = (const float4*)(out + src1 * 16 + dbase);
      oQ0 = op[0];
      oQ1 = op[1];
    }
  }

  for (int c = wave; c < NCHUNK; c += nw) {
    // ---- issue index loads 3 ahead, ea 2 ahead ----
    int src3 = 0;
    float4 avN = {0.f, 0.f, 0.f, 0.f};
    if (c + 3 * nw < NCHUNK) src3 = ei[(c + 3 * nw) * 16 + n];
    if (c + 2 * nw < NCHUNK) avN = ((const float4*)ea)[(c + 2 * nw) * 16 + n];
    // ---- issue out-gather 2 ahead (src2 arrived) ----
    float4 oR0 = {0.f, 0.f, 0.f, 0.f}, oR1 = {0.f, 0.f, 0.f, 0.f};
    if (c + 2 * nw < NCHUNK) {
      const float4* op = (const float4*)(out + src2 * 16 + dbase);
      oR0 = op[0];
      oR1 = op[1];
    }
    // ---- slot for current chunk (coalesced; hides under compute) ----
    int4 sl = *(const int4*)(slot + c * 16 + q * 4);

    // ---- compute with P-state ----
    // convert o to f16 once per chunk; products are packed f16 mul
    half8 o8;
    o8[0] = (_Float16)oP0.x; o8[1] = (_Float16)oP0.y;
    o8[2] = (_Float16)oP0.z; o8[3] = (_Float16)oP0.w;
    o8[4] = (_Float16)oP1.x; o8[5] = (_Float16)oP1.y;
    o8[6] = (_Float16)oP1.z; o8[7] = (_Float16)oP1.w;
    half8 ob;  // bias-step A operand
#pragma unroll
    for (int i = 0; i < 8; ++i) ob[i] = (q < 2) ? o8[i] : (_Float16)0.f;

    f32x4 acc = {0.f, 0.f, 0.f, 0.f};
#pragma unroll
    for (int s = 0; s < 16; ++s) {
      float4 wj = *(const float4*)&sW1T[(p * 16 + s) * 4];
      float he_s = fmaxf(sbe1[p * 16 + s] + avP.x * wj.x + avP.y * wj.y +
                             avP.z * wj.z + avP.w * wj.w,
                         0.f);
      _Float16 heh = (_Float16)he_s;
      half8 hev;
#pragma unroll
      for (int i = 0; i < 8; ++i) hev[i] = heh;
      half8 av = hev * o8;  // 4x v_pk_mul_f16
      acc = __builtin_amdgcn_mfma_f32_16x16x32_f16(av, bfrag[s], acc, 0, 0, 0);
    }
    acc = __builtin_amdgcn_mfma_f32_16x16x32_f16(ob, bfrag[16], acc, 0, 0, 0);

    __hip_bfloat16 b0 = __float2bfloat16(acc[0]);
    __hip_bfloat16 b1 = __float2bfloat16(acc[1]);
    __hip_bfloat16 b2 = __float2bfloat16(acc[2]);
    __hip_bfloat16 b3 = __float2bfloat16(acc[3]);
    m_bufh[(size_t)sl.x * 16 + n] = *(unsigned short*)&b0;
    m_bufh[(size_t)sl.y * 16 + n] = *(unsigned short*)&b1;
    m_bufh[(size_t)sl.z * 16 + n] = *(unsigned short*)&b2;
    m_bufh[(size_t)sl.w * 16 + n] = *(unsigned short*)&b3;

    // ---- rotate pipeline registers ----
    oP0 = oQ0; oP1 = oQ1; oQ0 = oR0; oQ1 = oR1;
    avP = avQ; avQ = avN;
    src2 = src3;
  }
}

// ---------------------------------------------------------------------------
// K4 (fused gather + GRU [+ final tail on last iter]): 16 lanes per node,
// 3125 blocks (round-10 measured optimum; round-9's 64-lane and round-11's
// grid-stride variants both regressed -- this form is converged).
// hk hoisted; segment sum unrolled x8.
// ---------------------------------------------------------------------------
__global__ __launch_bounds__(256) void gather_gru_kernel(
    const int* __restrict__ row_off, const unsigned short* __restrict__ m_bufh,
    const float* __restrict__ Wroot, const float* __restrict__ bconv,
    const float* __restrict__ Wih, const float* __restrict__ bih,
    const float* __restrict__ Whh, const float* __restrict__ bhh,
    float* __restrict__ out, int do_final, const int* __restrict__ node_type,
    const float* __restrict__ Wlin1, const float* __restrict__ blin1,
    const float* __restrict__ Wup, const float* __restrict__ bup,
    const float* __restrict__ Wdown, const float* __restrict__ bdown,
    const float* __restrict__ M_B, const float* __restrict__ M_A,
    const float* __restrict__ wedge, const float* __restrict__ Wline,
    const float* __restrict__ bline, float* __restrict__ res) {
  __shared__ float sWr[256];
  __shared__ float sWihT[768];  // [g*256 + d*16 + k] = Wih[(g*16+k)*16+d]
  __shared__ float sWhhT[768];
  __shared__ float sb[112];     // bconv[16] | bih[48] | bhh[48]
  int t = threadIdx.x;
  int kk = t >> 4, dd = t & 15;
  sWr[t] = Wroot[t];
#pragma unroll
  for (int g = 0; g < 3; ++g) {
    sWihT[g * 256 + dd * 16 + kk] = Wih[g * 256 + t];
    sWhhT[g * 256 + dd * 16 + kk] = Whh[g * 256 + t];
  }
  if (t < 16) sb[t] = bconv[t];
  else if (t < 64) sb[t] = bih[t - 16];
  else if (t < 112) sb[t] = bhh[t - 64];
  __syncthreads();

  int n = blockIdx.x * 16 + (t >> 4);
  int k = t & 15;
  int s0 = row_off[n], s1 = row_off[n + 1];

  float hk = out[n * 16 + k];  // independent load, in flight during the sum

  float aggk = 0.f;
  int j = s0;
  for (; j + 7 < s1; j += 8) {
    float a0 = bf16_to_f32(m_bufh[(size_t)(j + 0) * 16 + k]);
    float a1 = bf16_to_f32(m_bufh[(size_t)(j + 1) * 16 + k]);
    float a2 = bf16_to_f32(m_bufh[(size_t)(j + 2) * 16 + k]);
    float a3 = bf16_to_f32(m_bufh[(size_t)(j + 3) * 16 + k]);
    float a4 = bf16_to_f32(m_bufh[(size_t)(j + 4) * 16 + k]);
    float a5 = bf16_to_f32(m_bufh[(size_t)(j + 5) * 16 + k]);
    float a6 = bf16_to_f32(m_bufh[(size_t)(j + 6) * 16 + k]);
    float a7 = bf16_to_f32(m_bufh[(size_t)(j + 7) * 16 + k]);
    aggk += ((a0 + a1) + (a2 + a3)) + ((a4 + a5) + (a6 + a7));
  }
  for (; j + 3 < s1; j += 4) {
    float a0 = bf16_to_f32(m_bufh[(size_t)(j + 0) * 16 + k]);
    float a1 = bf16_to_f32(m_bufh[(size_t)(j + 1) * 16 + k]);
    float a2 = bf16_to_f32(m_bufh[(size_t)(j + 2) * 16 + k]);
    float a3 = bf16_to_f32(m_bufh[(size_t)(j + 3) * 16 + k]);
    aggk += (a0 + a1) + (a2 + a3);
  }
  for (; j < s1; ++j) aggk += bf16_to_f32(m_bufh[(size_t)j * 16 + k]);
  float sc = 1.f / fmaxf((float)(s1 - s0), 1.f);

  float mk = sb[k] + aggk * sc;
#pragma unroll
  for (int d = 0; d < 16; ++d) mk += __shfl(hk, d, 16) * sWr[d * 16 + k];
  mk = fmaxf(mk, 0.f);

  float gir = sb[16 + k], giz = sb[32 + k], gin = sb[48 + k];
  float ghr = sb[64 + k], ghz = sb[80 + k], ghn = sb[96 + k];
#pragma unroll
  for (int d = 0; d < 16; ++d) {
    float md = __shfl(mk, d, 16);
    float hd = __shfl(hk, d, 16);
    gir += md * sWihT[d * 16 + k];
    giz += md * sWihT[256 + d * 16 + k];
    gin += md * sWihT[512 + d * 16 + k];
    ghr += hd * sWhhT[d * 16 + k];
    ghz += hd * sWhhT[256 + d * 16 + k];
    ghn += hd * sWhhT[512 + d * 16 + k];
  }
  float r = 1.f / (1.f + __expf(-(gir + ghr)));
  float z = 1.f / (1.f + __expf(-(giz + ghz)));
  float xn = gin + r * ghn;
  float ng = 1.f - 2.f / (__expf(2.f * xn) + 1.f);  // tanh, saturates safely
  float hnew = (1.f - z) * ng + z * hk;

  if (!do_final) {
    out[n * 16 + k] = hnew;
    return;
  }

  // ---- fused tail (reference post-loop; only out_edges branch is live) ----
  float p0 = hnew * Wlin1[k * 4 + 0];
  float p1 = hnew * Wlin1[k * 4 + 1];
  float p2 = hnew * Wlin1[k * 4 + 2];
  float p3 = hnew * Wlin1[k * 4 + 3];
#pragma unroll
  for (int msk = 1; msk < 16; msk <<= 1) {
    p0 += __shfl_xor(p0, msk, 16);
    p1 += __shfl_xor(p1, msk, 16);
    p2 += __shfl_xor(p2, msk, 16);
    p3 += __shfl_xor(p3, msk, 16);
  }
  float oe0 = fmaxf(p0 + blin1[0], 0.f);
  float oe1 = fmaxf(p1 + blin1[1], 0.f);
  float oe2 = fmaxf(p2 + blin1[2], 0.f);
  float oe3 = fmaxf(p3 + blin1[3], 0.f);

  bool ev = (node_type[n] == 2);
  float ock = ev ? (bup[k] + oe0 * Wup[k] + oe1 * Wup[16 + k] +
                    oe2 * Wup[32 + k] + oe3 * Wup[48 + k])
                 : hnew;

  float msgBk = 0.f;
#pragma unroll
  for (int d = 0; d < 16; ++d) msgBk += __shfl(ock, d, 16) * M_B[d * 16 + k];
  msgBk = fmaxf(msgBk, 0.f);

  float q0 = msgBk * Wdown[k * 4 + 0];
  float q1 = msgBk * Wdown[k * 4 + 1];
  float q2 = msgBk * Wdown[k * 4 + 2];
  float q3 = msgBk * Wdown[k * 4 + 3];
#pragma unroll
  for (int msk = 1; msk < 16; msk <<= 1) {
    q0 += __shfl_xor(q0, msk, 16);
    q1 += __shfl_xor(q1, msk, 16);
    q2 += __shfl_xor(q2, msk, 16);
    q3 += __shfl_xor(q3, msk, 16);
  }
  float mtb0 = q0 + bdown[0], mtb1 = q1 + bdown[1];
  float mtb2 = q2 + bdown[2], mtb3 = q3 + bdown[3];

  float mta0 = fmaxf(oe0 * M_A[0] + oe1 * M_A[4] + oe2 * M_A[8] + oe3 * M_A[12], 0.f);
  float mta1 = fmaxf(oe0 * M_A[1] + oe1 * M_A[5] + oe2 * M_A[9] + oe3 * M_A[13], 0.f);
  float mta2 = fmaxf(oe0 * M_A[2] + oe1 * M_A[6] + oe2 * M_A[10] + oe3 * M_A[14], 0.f);
  float mta3 = fmaxf(oe0 * M_A[3] + oe1 * M_A[7] + oe2 * M_A[11] + oe3 * M_A[15], 0.f);

  float c0 = wedge[0] * (mta0 * mtb0);
  float c1 = wedge[1] * (mta1 * mtb1);
  float c2 = wedge[2] * (mta2 * mtb2);
  float c3 = wedge[3] * (mta3 * mtb3);

  float f0 = oe0 + fmaxf(bline[0] + c0 * Wline[0] + c1 * Wline[4] +
                         c2 * Wline[8] + c3 * Wline[12], 0.f);
  float f1 = oe1 + fmaxf(bline[1] + c0 * Wline[1] + c1 * Wline[5] +
                         c2 * Wline[9] + c3 * Wline[13], 0.f);
  float f2 = oe2 + fmaxf(bline[2] + c0 * Wline[2] + c1 * Wline[6] +
                         c2 * Wline[10] + c3 * Wline[14], 0.f);
  float f3 = oe3 + fmaxf(bline[3] + c0 * Wline[3] + c1 * Wline[7] +
                         c2 * Wline[11] + c3 * Wline[15], 0.f);

  float mx = fmaxf(fmaxf(f0, f1), fmaxf(f2, f3));
  float se = __expf(f0 - mx) + __expf(f1 - mx) + __expf(f2 - mx) +
             __expf(f3 - mx);
  float lse = mx + __logf(se);
  if (k < 4) {
    float v = (k == 0) ? f0 : (k == 1) ? f1 : (k == 2) ? f2 : f3;
    res[n * 4 + k] = v - lse;
  }
}

// ---------------------------------------------------------------------------
extern "C" void kernel_launch(void* const* d_in, const int* in_sizes, int n_in,
                              void* d_out, int out_size, void* d_ws,
                              size_t ws_size, hipStream_t stream) {
  const float* x       = (const float*)d_in[0];
  const int* node_type = (const int*)d_in[1];
  const int* ei        = (const int*)d_in[2];
  const float* ea      = (const float*)d_in[3];
  const float* W_lin0  = (const float*)d_in[4];
  const float* b_lin0  = (const float*)d_in[5];
  const float* W_root  = (const float*)d_in[6];
  const float* b_conv  = (const float*)d_in[7];
  const float* W_e1    = (const float*)d_in[8];
  const float* b_e1    = (const float*)d_in[9];
  const float* W_e2    = (const float*)d_in[10];
  const float* b_e2    = (const float*)d_in[11];
  const float* W_ih    = (const float*)d_in[12];
  const float* b_ih    = (const float*)d_in[13];
  const float* W_hh    = (const float*)d_in[14];
  const float* b_hh    = (const float*)d_in[15];
  const float* W_lin1  = (const float*)d_in[16];
  const float* b_lin1  = (const float*)d_in[17];
  const float* W_up    = (const float*)d_in[18];
  const float* b_up    = (const float*)d_in[19];
  const float* W_down  = (const float*)d_in[20];
  const float* b_down  = (const float*)d_in[21];
  const float* U_B     = (const float*)d_in[22];
  const float* V_B     = (const float*)d_in[23];
  // d_in[24..25] U_C,V_C and d_in[28..30] w_node,W_lin,b_lin : dead code
  const float* U_A     = (const float*)d_in[26];
  const float* V_A     = (const float*)d_in[27];
  const float* w_edge  = (const float*)d_in[31];
  const float* W_line  = (const float*)d_in[32];
  const float* b_line  = (const float*)d_in[33];

  float* ws    = (float*)d_ws;
  float* out   = ws;                                        // N*16 f32
  unsigned short* m_bufh = (unsigned short*)(out + N_NODES * 16);  // E*16 u16
  float* M_B   = (float*)(m_bufh + (size_t)N_EDGES * 16);   // 256
  float* M_A   = M_B + 256;                                 // 16
  int* degI    = (int*)(M_A + 16);                          // N
  int* ticket  = degI + N_NODES;                            // 1
  int* st      = ticket + 1;                                // 63 (pad)
  int* row_off = st + 63;                                   // N+1
  int* rank    = row_off + N_NODES + 1;                     // E
  int* slot    = rank + N_EDGES;                            // E

  // zero degI + ticket + st in one memset
  hipMemsetAsync(degI, 0, (N_NODES + 64) * sizeof(int), stream);

  setup_kernel<<<E_BLOCKS, 256, 0, stream>>>(x, W_lin0, b_lin0, ei, U_B, V_B,
                                             U_A, V_A, out, degI, rank, M_B,
                                             M_A);
  scan_kernel<<<SCAN_BLOCKS, 256, 0, stream>>>(degI, ticket, st, row_off);
  slot_kernel<<<E_BLOCKS, 256, 0, stream>>>(ei, row_off, rank, slot);

  for (int it = 0; it < 3; ++it) {
    edge_msg_mfma_kernel<<<EDGE_GRID, 256, 0, stream>>>(
        ei, ea, W_e1, b_e1, W_e2, b_e2, out, slot, m_bufh);
    gather_gru_kernel<<<N_NODES / 16, 256, 0, stream>>>(
        row_off, m_bufh, W_root, b_conv, W_ih, b_ih, W_hh, b_hh, out,
        (it == 2) ? 1 : 0, node_type, W_lin1, b_lin1, W_up, b_up, W_down,
        b_down, M_B, M_A, w_edge, W_line, b_line, (float*)d_out);
  }
}